// Round 8
// baseline (455.706 us; speedup 1.0000x reference)
//
#include <hip/hip_runtime.h>
#include <hip/hip_bf16.h>

// Problem constants (fixed by the reference)
#define NN 100000
#define EE 1600000
#define NODE_DIM 128
#define HID 64
#define NGRAPH 256
#define BN_EPS 1e-5f

// counting-sort geometry
#define NB 196            // coarse buckets: dst>>9  (99999>>9 == 195)
#define BW 512            // bucket width (power of 2)
#define CH 4096           // edges per chunk
#define NCHUNK 391        // ceil(EE/CH)
#define MHIST (NB * NCHUNK)   // 76636
#define MAXB 12288        // LDS capacity per bucket (avg 8192)

typedef __attribute__((ext_vector_type(8))) short short8;   // 8 bf16 (4 VGPRs)
typedef __attribute__((ext_vector_type(4))) float f32x4;    // MFMA acc

// RNE float->bf16 (bit-exact)
static __device__ __forceinline__ unsigned short f2bf(float f) {
    unsigned u = __float_as_uint(f);
    unsigned r = (u + 0x7fffu + ((u >> 16) & 1u)) >> 16;
    return (unsigned short)r;
}
static __device__ __forceinline__ float bf2f(unsigned short u) {
    return __uint_as_float(((unsigned)u) << 16);
}

// ---------------- workspace layout (units of 4 bytes) ----------------
#define I_OFF   0                 // int[NN+1]
#define I_DEG   100032            // int[NN]
#define I_HIST  200064            // int[MHIST]
#define I_HS    276864            // int[MHIST] (scanned)
#define I_BS    353664            // int[128]
#define I_BO    353792            // int[128]
#define I_PAIR  353920            // int2[EE]  (3,200,000 words)
#define I_SRCS  3553920           // int[EE]   sorted csrc
#define I_DINV  5153920           // float[NN]
#define I_WC    5253952           // float[128*64 + 64]
#define I_WFA   5262208           // bf16[128*64]  (4096 words)
#define I_WF1   5266304           // bf16[64*64]   (2048 words)
#define I_WF2   5268352           // bf16[64*64]   (2048 words)
#define I_BUFA  5270400           // bf16[NN*64]  (3,200,000 words)
#define I_BUFB  8470400           // bf16[NN*64]  (3,200,000 words)
#define I_SUMS  11670400          // float[NGRAPH*HID] (16384 words)
#define I_SCSH  11686784          // float[3*128]  (BN scale/shift table)
#define I_WS    11687168          // float[EE]  per-edge src weight
// end = 13,287,168 words = 53.1 MB

// ---------------- pass A: per-chunk coarse histogram ----------------
__global__ __launch_bounds__(256) void hist_k(const int* __restrict__ dst,
                                              int* __restrict__ hist) {
    __shared__ int h[NB];
    for (int i = threadIdx.x; i < NB; i += 256) h[i] = 0;
    __syncthreads();
    int base = blockIdx.x * CH + threadIdx.x;
    #pragma unroll
    for (int j = 0; j < 16; ++j) {
        int e = base + j * 256;
        if (e < EE) {
            int d = __builtin_nontemporal_load(dst + e);
            atomicAdd(&h[d >> 9], 1);
        }
    }
    __syncthreads();
    for (int i = threadIdx.x; i < NB; i += 256)
        hist[i * NCHUNK + blockIdx.x] = h[i];   // bucket-major for the scan
}

// ---------------- generic exclusive scan (3 stages) ----------------
__global__ void scan1_k(const int* __restrict__ in, int* __restrict__ part,
                        int* __restrict__ bsums, int n) {
    __shared__ int wsum[4];
    __shared__ int woff[4];
    int t = threadIdx.x;
    int base = blockIdx.x * 1024 + t * 4;
    int v0 = 0, v1 = 0, v2 = 0, v3 = 0;
    if (base + 3 < n) {
        v0 = in[base]; v1 = in[base + 1]; v2 = in[base + 2]; v3 = in[base + 3];
    } else {
        if (base     < n) v0 = in[base];
        if (base + 1 < n) v1 = in[base + 1];
        if (base + 2 < n) v2 = in[base + 2];
    }
    int s = v0 + v1 + v2 + v3;
    int lane = t & 63, wid = t >> 6;
    int x = s;
    #pragma unroll
    for (int d = 1; d < 64; d <<= 1) {
        int y = __shfl_up(x, d, 64);
        if (lane >= d) x += y;
    }
    if (lane == 63) wsum[wid] = x;
    __syncthreads();
    if (t == 0) {
        int r = 0;
        for (int w = 0; w < 4; ++w) { woff[w] = r; r += wsum[w]; }
        bsums[blockIdx.x] = r;
    }
    __syncthreads();
    int ex = woff[wid] + (x - s);
    if (base     < n) part[base]     = ex;
    if (base + 1 < n) part[base + 1] = ex + v0;
    if (base + 2 < n) part[base + 2] = ex + v0 + v1;
    if (base + 3 < n) part[base + 3] = ex + v0 + v1 + v2;
}

__global__ void scan2_k(const int* __restrict__ bsums, int* __restrict__ boffs, int nb) {
    __shared__ int wsum[2];
    __shared__ int woff2[2];
    int t = threadIdx.x;
    int v = (t < nb) ? bsums[t] : 0;
    int lane = t & 63, wid = t >> 6;
    int x = v;
    #pragma unroll
    for (int d = 1; d < 64; d <<= 1) {
        int y = __shfl_up(x, d, 64);
        if (lane >= d) x += y;
    }
    if (lane == 63) wsum[wid] = x;
    __syncthreads();
    if (t == 0) { woff2[0] = 0; woff2[1] = wsum[0]; }
    __syncthreads();
    int ex = woff2[wid] + (x - v);
    if (t < nb) boffs[t] = ex;
}

__global__ void scan3g_k(int* __restrict__ arr, const int* __restrict__ boffs, int n) {
    int i = blockIdx.x * 256 + threadIdx.x;
    if (i < n) arr[i] += boffs[i >> 10];
}

// ---------------- pass B: coarse placement (dst,src) pairs by bucket ----------------
__global__ __launch_bounds__(256) void sortB_k(const int* __restrict__ srcA,
                                               const int* __restrict__ dstA,
                                               const int* __restrict__ hs,
                                               int2* __restrict__ pair) {
    __shared__ int lcur[NB];
    for (int i = threadIdx.x; i < NB; i += 256)
        lcur[i] = hs[i * NCHUNK + blockIdx.x];
    __syncthreads();
    int base = blockIdx.x * CH + threadIdx.x;
    #pragma unroll
    for (int j = 0; j < 16; ++j) {
        int e = base + j * 256;
        if (e < EE) {
            int d = __builtin_nontemporal_load(dstA + e);
            int s = __builtin_nontemporal_load(srcA + e);
            int pos = atomicAdd(&lcur[d >> 9], 1);
            pair[pos] = make_int2(d, s);
        }
    }
}

// ---------------- pass C: per-bucket exact sort in LDS; emits deg/off/csrc ----------------
__global__ __launch_bounds__(256) void fineC_k(const int2* __restrict__ pair,
                                               const int* __restrict__ hs,
                                               int* __restrict__ deg,
                                               int* __restrict__ off,
                                               int* __restrict__ csrc) {
    __shared__ int cnt[BW];
    __shared__ int loff[BW];
    __shared__ int wsum[4];
    __shared__ int woff[4];
    __shared__ int ssrc[MAXB];
    int b = blockIdx.x;
    int t = threadIdx.x;
    int base = hs[b * NCHUNK];
    int end  = (b == NB - 1) ? EE : hs[(b + 1) * NCHUNK];
    int m = end - base;

    for (int i = t; i < BW; i += 256) cnt[i] = 0;
    __syncthreads();
    for (int i = t; i < m; i += 256) {
        int2 p = pair[base + i];
        atomicAdd(&cnt[p.x & (BW - 1)], 1);
    }
    __syncthreads();

    int c0 = cnt[2 * t], c1 = cnt[2 * t + 1];
    int s = c0 + c1;
    int lane = t & 63, wid = t >> 6;
    int x = s;
    #pragma unroll
    for (int d = 1; d < 64; d <<= 1) {
        int y = __shfl_up(x, d, 64);
        if (lane >= d) x += y;
    }
    if (lane == 63) wsum[wid] = x;
    __syncthreads();
    if (t == 0) {
        int r = 0;
        for (int w = 0; w < 4; ++w) { woff[w] = r; r += wsum[w]; }
    }
    __syncthreads();
    int ex = woff[wid] + (x - s);
    loff[2 * t] = ex;
    loff[2 * t + 1] = ex + c0;
    __syncthreads();

    int node0 = b << 9;
    for (int i = t; i < BW; i += 256) {
        int node = node0 + i;
        if (node < NN) { deg[node] = cnt[i]; off[node] = base + loff[i]; }
        else if (node == NN) { off[NN] = EE; }
    }
    __syncthreads();

    for (int i = t; i < BW; i += 256) cnt[i] = loff[i];
    __syncthreads();
    for (int i = t; i < m; i += 256) {
        int2 p = pair[base + i];
        int pos = atomicAdd(&cnt[p.x & (BW - 1)], 1);
        if (pos < MAXB) ssrc[pos] = p.y;
        else            csrc[base + pos] = p.y;   // statistically never taken
    }
    __syncthreads();
    int mm = m < MAXB ? m : MAXB;
    for (int i = t; i < mm; i += 256) csrc[base + i] = ssrc[i];   // coalesced
}

__global__ void dinv_k(const int* __restrict__ cnt, float* __restrict__ dinv, int n) {
    int i = blockIdx.x * 256 + threadIdx.x;
    if (i < n) dinv[i] = rsqrtf((float)(cnt[i] + 1));   // +1 self loop
}

// per-edge source weight: ws[e] = dinv[csrc[e]]  (coalesced read/write, tiny gather)
__global__ void wsrc_k(const int* __restrict__ csrc, const float* __restrict__ dinv,
                       float* __restrict__ ws) {
    int e = blockIdx.x * 256 + threadIdx.x;
    if (e < EE) ws[e] = dinv[csrc[e]];
}

// ---------------- BN scale/shift table: sc = g*rsqrt(v+eps), sh = (cb-m)*sc+b ----------------
__global__ void bnprep_k(const float* __restrict__ convb, const float* __restrict__ gamma,
                         const float* __restrict__ beta, const float* __restrict__ mean,
                         const float* __restrict__ var, float* __restrict__ scsh) {
    int t = blockIdx.x * 64 + threadIdx.x;   // grid 3 x 64
    int l = t >> 6, c = t & 63;
    float sc = gamma[l * 64 + c] * rsqrtf(var[l * 64 + c] + BN_EPS);
    float sh = (convb[l * 64 + c] - mean[l * 64 + c]) * sc + beta[l * 64 + c];
    scsh[l * 128 + c] = sc;
    scsh[l * 128 + 64 + c] = sh;
}

// ---------------- fused input-proj weight: Wc = W_in @ conv_W0, bc = b_in @ conv_W0 ----------------
__global__ void wc_k(const float* __restrict__ Win, const float* __restrict__ bin,
                     const float* __restrict__ cw0, float* __restrict__ Wc) {
    int idx = blockIdx.x * 256 + threadIdx.x;
    if (idx < NODE_DIM * HID) {
        int k = idx >> 6, c = idx & 63;
        float a = 0.f;
        #pragma unroll 8
        for (int j = 0; j < HID; ++j) a += Win[k * HID + j] * cw0[j * HID + c];
        Wc[idx] = a;
    } else if (idx < NODE_DIM * HID + HID) {
        int c = idx - NODE_DIM * HID;
        float a = 0.f;
        #pragma unroll 8
        for (int j = 0; j < HID; ++j) a += bin[j] * cw0[j * HID + c];
        Wc[idx] = a;
    }
}

// ---------------- pack W into MFMA B-fragment order (bf16) ----------------
__global__ __launch_bounds__(256) void wfrag_k(const float* __restrict__ Wc,
                                               const float* __restrict__ convW,
                                               short* __restrict__ WfA,
                                               short* __restrict__ Wf1,
                                               short* __restrict__ Wf2) {
    int id = blockIdx.x * 256 + threadIdx.x;   // 0..2047
    const float* W; short* out; int u;
    if (id < 1024)      { W = Wc;           out = WfA; u = id; }
    else if (id < 1536) { W = convW + 4096; out = Wf1; u = id - 1024; }
    else                { W = convW + 8192; out = Wf2; u = id - 1536; }
    int l = u & 63, t = (u >> 6) & 3, s = u >> 8;
    int k0 = s * 32 + ((l >> 4) & 3) * 8;
    int col = t * 16 + (l & 15);
    short8 v;
    #pragma unroll
    for (int j = 0; j < 8; ++j) v[j] = (short)f2bf(W[(k0 + j) * 64 + col]);
    *(short8*)(out + u * 8) = v;
}

// ---------------- MFMA transform: out[n,64] = bf16(in[n,K] @ W[K,64] (+bias)) ----------------
template <int K, bool BIAS, bool A_BF16>
__global__ __launch_bounds__(256, 4) void gemm_k(const void* __restrict__ inv,
                                                 const short8* __restrict__ Wf,
                                                 const float* __restrict__ bias,
                                                 __hip_bfloat16* __restrict__ out) {
    constexpr int NS = K / 32;
    int l = threadIdx.x & 63;
    int w = threadIdx.x >> 6;
    int rows0 = blockIdx.x * 64 + w * 16;
    int arow = rows0 + (l & 15);
    bool rok = arow < NN;
    int kgrp = (l >> 4) & 3;

    short8 wf[NS][4];
    #pragma unroll
    for (int s = 0; s < NS; ++s)
        #pragma unroll
        for (int t = 0; t < 4; ++t)
            wf[s][t] = Wf[(s * 4 + t) * 64 + l];

    f32x4 acc[4];
    #pragma unroll
    for (int t = 0; t < 4; ++t) acc[t] = (f32x4){0.f, 0.f, 0.f, 0.f};

    #pragma unroll
    for (int s = 0; s < NS; ++s) {
        short8 af = {0, 0, 0, 0, 0, 0, 0, 0};
        if (A_BF16) {
            if (rok)
                af = *(const short8*)((const short*)inv + (long)arow * K + s * 32 + kgrp * 8);
        } else {
            if (rok) {
                const float* ap = (const float*)inv + (long)arow * K + s * 32 + kgrp * 8;
                float4 a0 = *(const float4*)ap;
                float4 a1 = *(const float4*)(ap + 4);
                af[0] = (short)f2bf(a0.x); af[1] = (short)f2bf(a0.y);
                af[2] = (short)f2bf(a0.z); af[3] = (short)f2bf(a0.w);
                af[4] = (short)f2bf(a1.x); af[5] = (short)f2bf(a1.y);
                af[6] = (short)f2bf(a1.z); af[7] = (short)f2bf(a1.w);
            }
        }
        #pragma unroll
        for (int t = 0; t < 4; ++t)
            acc[t] = __builtin_amdgcn_mfma_f32_16x16x32_bf16(af, wf[s][t], acc[t], 0, 0, 0);
    }

    // C/D layout: col = lane&15, row = (lane>>4)*4 + reg  [m89-verified]
    int orow0 = rows0 + kgrp * 4;
    #pragma unroll
    for (int t = 0; t < 4; ++t) {
        int col = t * 16 + (l & 15);
        float b = BIAS ? bias[col] : 0.f;
        #pragma unroll
        for (int r = 0; r < 4; ++r) {
            int row = orow0 + r;
            if (row < NN)
                out[(long)row * HID + col] = __float2bfloat16(acc[t][r] + b);
        }
    }
}

// ---------------- aggregate: out[i] = relu(BN(selfloop + sum_edges)) ----------------
// one wave per node, lane = channel (contiguous 128 B per gather); CSR walk on
// the scalar path (i forced wave-uniform); 8 independent row-gathers in flight.
__global__ __launch_bounds__(256) void aggregate_k(const unsigned short* __restrict__ hw,
                                                   const int* __restrict__ off,
                                                   const int* __restrict__ src,
                                                   const float* __restrict__ ws,
                                                   const float* __restrict__ dinv,
                                                   const float* __restrict__ scsh,
                                                   unsigned short* __restrict__ out) {
    int lane = threadIdx.x & 63;
    int i = __builtin_amdgcn_readfirstlane((int)blockIdx.x * 4 + (threadIdx.x >> 6));
    float di = dinv[i];
    int e0 = off[i], e1 = off[i + 1];

    float acc = bf2f(hw[(long)i * HID + lane]) * di * di;   // self loop

    int nit = (e1 - e0 + 7) >> 3;   // wave-uniform
    for (int it = 0; it < nit; ++it) {
        int eb = e0 + it * 8;
        int sx[8]; float wx[8];
        #pragma unroll
        for (int j = 0; j < 8; ++j) {
            int ee = eb + j;
            bool ok = ee < e1;
            sx[j] = src[ok ? ee : e0];
            wx[j] = ok ? ws[ee] * di : 0.f;
        }
        float h[8];
        #pragma unroll
        for (int j = 0; j < 8; ++j)
            h[j] = bf2f(hw[(long)sx[j] * HID + lane]);   // 8 gathers in flight
        #pragma unroll
        for (int j = 0; j < 8; ++j)
            acc += h[j] * wx[j];
    }

    float sc = scsh[lane];
    float sh = scsh[64 + lane];
    out[(long)i * HID + lane] = f2bf(fmaxf(acc * sc + sh, 0.f));
}

// ---------------- pooling stage 1: parallel segmented sum over sorted batch ----------------
__global__ __launch_bounds__(256) void pool1_k(const __hip_bfloat16* __restrict__ h,
                                               const int* __restrict__ batch,
                                               float* __restrict__ sums) {
    int lane = threadIdx.x & 63;
    int wid = threadIdx.x >> 6;
    int chunk = blockIdx.x * 4 + wid;
    int i0 = chunk * 64;
    if (i0 >= NN) return;
    int i1 = i0 + 64;
    if (i1 > NN) i1 = NN;
    int g = batch[i0];
    float acc = 0.f;
    for (int i = i0; i < i1; ++i) {
        int bi = batch[i];
        if (bi != g) {
            atomicAdd(&sums[g * HID + lane], acc);
            acc = 0.f;
            g = bi;
        }
        acc += __bfloat162float(h[(long)i * HID + lane]);
    }
    atomicAdd(&sums[g * HID + lane], acc);
}

// ---------------- pooling stage 2 + 3-layer MLP, one block per graph ----------------
__device__ __forceinline__ int lower_bound_i(const int* __restrict__ a, int n, int key) {
    int lo = 0, hi = n;
    while (lo < hi) {
        int m = (lo + hi) >> 1;
        if (a[m] < key) lo = m + 1; else hi = m;
    }
    return lo;
}

__global__ __launch_bounds__(64) void mlp_k(const float* __restrict__ sums,
                                            const int* __restrict__ batch,
                                            const float* __restrict__ W1, const float* __restrict__ b1,
                                            const float* __restrict__ W2, const float* __restrict__ b2,
                                            const float* __restrict__ W3, const float* __restrict__ b3,
                                            float* __restrict__ out) {
    int g = blockIdx.x;
    int lane = threadIdx.x;
    int start = lower_bound_i(batch, NN, g);
    int end = lower_bound_i(batch, NN, g + 1);
    float cnt = (float)(end - start);
    float gv = sums[g * HID + lane] / fmaxf(cnt, 1.0f);

    __shared__ float gs[HID];
    __shared__ float h1s[HID];
    gs[lane] = gv;
    __syncthreads();

    float a1 = b1[lane];
    #pragma unroll 8
    for (int k = 0; k < HID; ++k) a1 += gs[k] * W1[k * HID + lane];
    a1 = fmaxf(a1, 0.f);
    h1s[lane] = a1;
    __syncthreads();

    float a2 = 0.f;
    if (lane < 32) {
        a2 = b2[lane];
        #pragma unroll 8
        for (int k = 0; k < HID; ++k) a2 += h1s[k] * W2[k * 32 + lane];
        a2 = fmaxf(a2, 0.f);
    }
    float p = (lane < 32) ? a2 * W3[lane] : 0.f;
    #pragma unroll
    for (int d = 32; d >= 1; d >>= 1) p += __shfl_down(p, d, 64);
    if (lane == 0) out[g] = p + b3[0];
}

// ---------------- host launch ----------------
extern "C" void kernel_launch(void* const* d_in, const int* in_sizes, int n_in,
                              void* d_out, int out_size, void* d_ws, size_t ws_size,
                              hipStream_t stream) {
    (void)in_sizes; (void)n_in; (void)out_size; (void)ws_size;

    const float* x      = (const float*)d_in[0];
    const int*   eidx   = (const int*)d_in[1];      // [2,E]: src then dst
    const int*   batch  = (const int*)d_in[2];
    const float* W_in   = (const float*)d_in[3];
    const float* b_in   = (const float*)d_in[4];
    const float* conv_W = (const float*)d_in[5];    // [3,64,64]
    const float* conv_b = (const float*)d_in[6];    // [3,64]
    const float* gamma  = (const float*)d_in[7];
    const float* beta   = (const float*)d_in[8];
    const float* mean   = (const float*)d_in[9];
    const float* var    = (const float*)d_in[10];
    const float* W1     = (const float*)d_in[11];
    const float* b1     = (const float*)d_in[12];
    const float* W2     = (const float*)d_in[13];
    const float* b2     = (const float*)d_in[14];
    const float* W3     = (const float*)d_in[15];
    const float* b3     = (const float*)d_in[16];
    float* outp = (float*)d_out;

    int*   wsi = (int*)d_ws;
    float* wsf = (float*)d_ws;

    int*   off    = wsi + I_OFF;
    int*   deg    = wsi + I_DEG;
    int*   hist   = wsi + I_HIST;
    int*   hs     = wsi + I_HS;
    int*   bsums  = wsi + I_BS;
    int*   boffs  = wsi + I_BO;
    int2*  pair   = (int2*)(wsi + I_PAIR);
    int*   csrc   = wsi + I_SRCS;
    float* dinv   = wsf + I_DINV;
    float* Wc     = wsf + I_WC;
    short* WfA    = (short*)(wsi + I_WFA);
    short* Wf1    = (short*)(wsi + I_WF1);
    short* Wf2    = (short*)(wsi + I_WF2);
    __hip_bfloat16* bufA = (__hip_bfloat16*)(wsf + I_BUFA);
    __hip_bfloat16* bufB = (__hip_bfloat16*)(wsf + I_BUFB);
    float* sums   = wsf + I_SUMS;
    float* scsh   = wsf + I_SCSH;
    float* ws     = wsf + I_WS;

    const int* esrc = eidx;
    const int* edst = eidx + EE;

    hipMemsetAsync(sums, 0, NGRAPH * HID * sizeof(float), stream);

    // ---- graph prep: two-level counting sort -> deg, off, csrc (coalesced writes)
    hist_k<<<NCHUNK, 256, 0, stream>>>(edst, hist);
    int nb1 = (MHIST + 1023) / 1024;                 // 75
    scan1_k<<<nb1, 256, 0, stream>>>(hist, hs, bsums, MHIST);
    scan2_k<<<1, 128, 0, stream>>>(bsums, boffs, nb1);
    scan3g_k<<<(MHIST + 255) / 256, 256, 0, stream>>>(hs, boffs, MHIST);
    wc_k<<<(NODE_DIM * HID + HID + 255) / 256, 256, 0, stream>>>(W_in, b_in, conv_W, Wc);
    wfrag_k<<<8, 256, 0, stream>>>(Wc, conv_W, WfA, Wf1, Wf2);
    bnprep_k<<<3, 64, 0, stream>>>(conv_b, gamma, beta, mean, var, scsh);
    sortB_k<<<NCHUNK, 256, 0, stream>>>(esrc, edst, hs, pair);
    fineC_k<<<NB, 256, 0, stream>>>(pair, hs, deg, off, csrc);
    dinv_k<<<(NN + 255) / 256, 256, 0, stream>>>(deg, dinv, NN);
    wsrc_k<<<(EE + 255) / 256, 256, 0, stream>>>(csrc, dinv, ws);

    int ngemm = (NN + 63) / 64;                 // 1563
    // layer 0: fused input projection + conv transform (A = x, fp32)
    gemm_k<NODE_DIM, true, false><<<ngemm, 256, 0, stream>>>(x, (const short8*)WfA,
                                                             Wc + NODE_DIM * HID, bufA);
    aggregate_k<<<NN / 4, 256, 0, stream>>>((const unsigned short*)bufA, off, csrc, ws, dinv,
                                            scsh + 0 * 128, (unsigned short*)bufB);
    // layer 1 (A = bufB, bf16)
    gemm_k<HID, false, true><<<ngemm, 256, 0, stream>>>(bufB, (const short8*)Wf1, nullptr, bufA);
    aggregate_k<<<NN / 4, 256, 0, stream>>>((const unsigned short*)bufA, off, csrc, ws, dinv,
                                            scsh + 1 * 128, (unsigned short*)bufB);
    // layer 2
    gemm_k<HID, false, true><<<ngemm, 256, 0, stream>>>(bufB, (const short8*)Wf2, nullptr, bufA);
    aggregate_k<<<NN / 4, 256, 0, stream>>>((const unsigned short*)bufA, off, csrc, ws, dinv,
                                            scsh + 2 * 128, (unsigned short*)bufB);

    // mean pool (parallel) + MLP
    pool1_k<<<(NN / 64 + 3) / 4, 256, 0, stream>>>(bufB, batch, sums);
    mlp_k<<<NGRAPH, 64, 0, stream>>>(sums, batch, W1, b1, W2, b2, W3, b3, outp);
}

// Round 9
// 418.988 us; speedup vs baseline: 1.0876x; 1.0876x over previous
//
#include <hip/hip_runtime.h>
#include <hip/hip_bf16.h>

// Problem constants (fixed by the reference)
#define NN 100000
#define EE 1600000
#define NODE_DIM 128
#define HID 64
#define NGRAPH 256
#define BN_EPS 1e-5f

// counting-sort geometry
#define NB 196            // coarse buckets: dst>>9  (99999>>9 == 195)
#define BW 512            // bucket width (power of 2)
#define CH 4096           // edges per chunk
#define NCHUNK 391        // ceil(EE/CH)
#define MHIST (NB * NCHUNK)   // 76636
#define MAXB 12288        // LDS capacity per bucket (avg 8192)

// aggregate geometry
#define DR 64             // dst rows per aggregate block

typedef __attribute__((ext_vector_type(8))) short short8;   // 8 bf16 (4 VGPRs)
typedef __attribute__((ext_vector_type(4))) float f32x4;    // MFMA acc

// RNE float->bf16 (bit-exact)
static __device__ __forceinline__ unsigned short f2bf(float f) {
    unsigned u = __float_as_uint(f);
    unsigned r = (u + 0x7fffu + ((u >> 16) & 1u)) >> 16;
    return (unsigned short)r;
}
static __device__ __forceinline__ float bf2f(unsigned short u) {
    return __uint_as_float(((unsigned)u) << 16);
}

// ---------------- workspace layout (units of 4 bytes) ----------------
#define I_OFF   0                 // int[NN+1]
#define I_DEG   100032            // int[NN]
#define I_HIST  200064            // int[MHIST]
#define I_HS    276864            // int[MHIST] (scanned)
#define I_BS    353664            // int[128]
#define I_BO    353792            // int[128]
#define I_PAIR  353920            // int2[EE]  (3,200,000 words)
#define I_SRCS  3553920           // int[EE]   sorted csrc
#define I_DINV  5153920           // float[NN]
#define I_WC    5253952           // float[128*64 + 64]
#define I_WFA   5262208           // bf16[128*64]  (4096 words)
#define I_WF1   5266304           // bf16[64*64]   (2048 words)
#define I_WF2   5268352           // bf16[64*64]   (2048 words)
#define I_BUFA  5270400           // bf16[NN*64]  (3,200,000 words)
#define I_BUFB  8470400           // bf16[NN*64]  (3,200,000 words)
#define I_SUMS  11670400          // float[NGRAPH*HID] (16384 words)
#define I_SCSH  11686784          // float[3*128]  (BN scale/shift table)
#define I_WS    11687168          // float[EE]  per-edge src weight
#define I_DST   13287168          // int[EE]    per-edge dst (sorted order)
// end = 14,887,168 words = 59.5 MB

// ---------------- pass A: per-chunk coarse histogram ----------------
__global__ __launch_bounds__(256) void hist_k(const int* __restrict__ dst,
                                              int* __restrict__ hist) {
    __shared__ int h[NB];
    for (int i = threadIdx.x; i < NB; i += 256) h[i] = 0;
    __syncthreads();
    int base = blockIdx.x * CH + threadIdx.x;
    #pragma unroll
    for (int j = 0; j < 16; ++j) {
        int e = base + j * 256;
        if (e < EE) {
            int d = __builtin_nontemporal_load(dst + e);
            atomicAdd(&h[d >> 9], 1);
        }
    }
    __syncthreads();
    for (int i = threadIdx.x; i < NB; i += 256)
        hist[i * NCHUNK + blockIdx.x] = h[i];   // bucket-major for the scan
}

// ---------------- generic exclusive scan (3 stages) ----------------
__global__ void scan1_k(const int* __restrict__ in, int* __restrict__ part,
                        int* __restrict__ bsums, int n) {
    __shared__ int wsum[4];
    __shared__ int woff[4];
    int t = threadIdx.x;
    int base = blockIdx.x * 1024 + t * 4;
    int v0 = 0, v1 = 0, v2 = 0, v3 = 0;
    if (base + 3 < n) {
        v0 = in[base]; v1 = in[base + 1]; v2 = in[base + 2]; v3 = in[base + 3];
    } else {
        if (base     < n) v0 = in[base];
        if (base + 1 < n) v1 = in[base + 1];
        if (base + 2 < n) v2 = in[base + 2];
    }
    int s = v0 + v1 + v2 + v3;
    int lane = t & 63, wid = t >> 6;
    int x = s;
    #pragma unroll
    for (int d = 1; d < 64; d <<= 1) {
        int y = __shfl_up(x, d, 64);
        if (lane >= d) x += y;
    }
    if (lane == 63) wsum[wid] = x;
    __syncthreads();
    if (t == 0) {
        int r = 0;
        for (int w = 0; w < 4; ++w) { woff[w] = r; r += wsum[w]; }
        bsums[blockIdx.x] = r;
    }
    __syncthreads();
    int ex = woff[wid] + (x - s);
    if (base     < n) part[base]     = ex;
    if (base + 1 < n) part[base + 1] = ex + v0;
    if (base + 2 < n) part[base + 2] = ex + v0 + v1;
    if (base + 3 < n) part[base + 3] = ex + v0 + v1 + v2;
}

__global__ void scan2_k(const int* __restrict__ bsums, int* __restrict__ boffs, int nb) {
    __shared__ int wsum[2];
    __shared__ int woff2[2];
    int t = threadIdx.x;
    int v = (t < nb) ? bsums[t] : 0;
    int lane = t & 63, wid = t >> 6;
    int x = v;
    #pragma unroll
    for (int d = 1; d < 64; d <<= 1) {
        int y = __shfl_up(x, d, 64);
        if (lane >= d) x += y;
    }
    if (lane == 63) wsum[wid] = x;
    __syncthreads();
    if (t == 0) { woff2[0] = 0; woff2[1] = wsum[0]; }
    __syncthreads();
    int ex = woff2[wid] + (x - v);
    if (t < nb) boffs[t] = ex;
}

__global__ void scan3g_k(int* __restrict__ arr, const int* __restrict__ boffs, int n) {
    int i = blockIdx.x * 256 + threadIdx.x;
    if (i < n) arr[i] += boffs[i >> 10];
}

// ---------------- pass B: coarse placement (dst,src) pairs by bucket ----------------
__global__ __launch_bounds__(256) void sortB_k(const int* __restrict__ srcA,
                                               const int* __restrict__ dstA,
                                               const int* __restrict__ hs,
                                               int2* __restrict__ pair) {
    __shared__ int lcur[NB];
    for (int i = threadIdx.x; i < NB; i += 256)
        lcur[i] = hs[i * NCHUNK + blockIdx.x];
    __syncthreads();
    int base = blockIdx.x * CH + threadIdx.x;
    #pragma unroll
    for (int j = 0; j < 16; ++j) {
        int e = base + j * 256;
        if (e < EE) {
            int d = __builtin_nontemporal_load(dstA + e);
            int s = __builtin_nontemporal_load(srcA + e);
            int pos = atomicAdd(&lcur[d >> 9], 1);
            pair[pos] = make_int2(d, s);
        }
    }
}

// ---------------- pass C: per-bucket exact sort in LDS; emits deg/off/csrc/cdst ----------------
// <=196 blocks (one per CU) so the 100 KB LDS footprint costs no occupancy.
__global__ __launch_bounds__(256) void fineC_k(const int2* __restrict__ pair,
                                               const int* __restrict__ hs,
                                               int* __restrict__ deg,
                                               int* __restrict__ off,
                                               int* __restrict__ csrc,
                                               int* __restrict__ cdst) {
    __shared__ int cnt[BW];
    __shared__ int loff[BW];
    __shared__ int wsum[4];
    __shared__ int woff[4];
    __shared__ int ssrc[MAXB];
    __shared__ int sdst[MAXB];
    int b = blockIdx.x;
    int t = threadIdx.x;
    int base = hs[b * NCHUNK];
    int end  = (b == NB - 1) ? EE : hs[(b + 1) * NCHUNK];
    int m = end - base;

    for (int i = t; i < BW; i += 256) cnt[i] = 0;
    __syncthreads();
    for (int i = t; i < m; i += 256) {
        int2 p = pair[base + i];
        atomicAdd(&cnt[p.x & (BW - 1)], 1);
    }
    __syncthreads();

    int c0 = cnt[2 * t], c1 = cnt[2 * t + 1];
    int s = c0 + c1;
    int lane = t & 63, wid = t >> 6;
    int x = s;
    #pragma unroll
    for (int d = 1; d < 64; d <<= 1) {
        int y = __shfl_up(x, d, 64);
        if (lane >= d) x += y;
    }
    if (lane == 63) wsum[wid] = x;
    __syncthreads();
    if (t == 0) {
        int r = 0;
        for (int w = 0; w < 4; ++w) { woff[w] = r; r += wsum[w]; }
    }
    __syncthreads();
    int ex = woff[wid] + (x - s);
    loff[2 * t] = ex;
    loff[2 * t + 1] = ex + c0;
    __syncthreads();

    int node0 = b << 9;
    for (int i = t; i < BW; i += 256) {
        int node = node0 + i;
        if (node < NN) { deg[node] = cnt[i]; off[node] = base + loff[i]; }
        else if (node == NN) { off[NN] = EE; }
    }
    __syncthreads();

    for (int i = t; i < BW; i += 256) cnt[i] = loff[i];
    __syncthreads();
    for (int i = t; i < m; i += 256) {
        int2 p = pair[base + i];
        int pos = atomicAdd(&cnt[p.x & (BW - 1)], 1);
        if (pos < MAXB) { ssrc[pos] = p.y; sdst[pos] = p.x; }
        else { csrc[base + pos] = p.y; cdst[base + pos] = p.x; }  // statistically never
    }
    __syncthreads();
    int mm = m < MAXB ? m : MAXB;
    for (int i = t; i < mm; i += 256) {   // coalesced copy-out
        csrc[base + i] = ssrc[i];
        cdst[base + i] = sdst[i];
    }
}

__global__ void dinv_k(const int* __restrict__ cnt, float* __restrict__ dinv, int n) {
    int i = blockIdx.x * 256 + threadIdx.x;
    if (i < n) dinv[i] = rsqrtf((float)(cnt[i] + 1));   // +1 self loop
}

// per-edge source weight: ws[e] = dinv[csrc[e]]
__global__ void wsrc_k(const int* __restrict__ csrc, const float* __restrict__ dinv,
                       float* __restrict__ ws) {
    int e = blockIdx.x * 256 + threadIdx.x;
    if (e < EE) ws[e] = dinv[csrc[e]];
}

// ---------------- BN scale/shift table ----------------
__global__ void bnprep_k(const float* __restrict__ convb, const float* __restrict__ gamma,
                         const float* __restrict__ beta, const float* __restrict__ mean,
                         const float* __restrict__ var, float* __restrict__ scsh) {
    int t = blockIdx.x * 64 + threadIdx.x;   // grid 3 x 64
    int l = t >> 6, c = t & 63;
    float sc = gamma[l * 64 + c] * rsqrtf(var[l * 64 + c] + BN_EPS);
    float sh = (convb[l * 64 + c] - mean[l * 64 + c]) * sc + beta[l * 64 + c];
    scsh[l * 128 + c] = sc;
    scsh[l * 128 + 64 + c] = sh;
}

// ---------------- fused input-proj weight: Wc = W_in @ conv_W0, bc = b_in @ conv_W0 ----------------
__global__ void wc_k(const float* __restrict__ Win, const float* __restrict__ bin,
                     const float* __restrict__ cw0, float* __restrict__ Wc) {
    int idx = blockIdx.x * 256 + threadIdx.x;
    if (idx < NODE_DIM * HID) {
        int k = idx >> 6, c = idx & 63;
        float a = 0.f;
        #pragma unroll 8
        for (int j = 0; j < HID; ++j) a += Win[k * HID + j] * cw0[j * HID + c];
        Wc[idx] = a;
    } else if (idx < NODE_DIM * HID + HID) {
        int c = idx - NODE_DIM * HID;
        float a = 0.f;
        #pragma unroll 8
        for (int j = 0; j < HID; ++j) a += bin[j] * cw0[j * HID + c];
        Wc[idx] = a;
    }
}

// ---------------- pack W into MFMA B-fragment order (bf16) ----------------
__global__ __launch_bounds__(256) void wfrag_k(const float* __restrict__ Wc,
                                               const float* __restrict__ convW,
                                               short* __restrict__ WfA,
                                               short* __restrict__ Wf1,
                                               short* __restrict__ Wf2) {
    int id = blockIdx.x * 256 + threadIdx.x;   // 0..2047
    const float* W; short* out; int u;
    if (id < 1024)      { W = Wc;           out = WfA; u = id; }
    else if (id < 1536) { W = convW + 4096; out = Wf1; u = id - 1024; }
    else                { W = convW + 8192; out = Wf2; u = id - 1536; }
    int l = u & 63, t = (u >> 6) & 3, s = u >> 8;
    int k0 = s * 32 + ((l >> 4) & 3) * 8;
    int col = t * 16 + (l & 15);
    short8 v;
    #pragma unroll
    for (int j = 0; j < 8; ++j) v[j] = (short)f2bf(W[(k0 + j) * 64 + col]);
    *(short8*)(out + u * 8) = v;
}

// ---------------- MFMA transform: out[n,64] = bf16(in[n,K] @ W[K,64] (+bias)) ----------------
template <int K, bool BIAS, bool A_BF16>
__global__ __launch_bounds__(256, 4) void gemm_k(const void* __restrict__ inv,
                                                 const short8* __restrict__ Wf,
                                                 const float* __restrict__ bias,
                                                 __hip_bfloat16* __restrict__ out) {
    constexpr int NS = K / 32;
    int l = threadIdx.x & 63;
    int w = threadIdx.x >> 6;
    int rows0 = blockIdx.x * 64 + w * 16;
    int arow = rows0 + (l & 15);
    bool rok = arow < NN;
    int kgrp = (l >> 4) & 3;

    short8 wf[NS][4];
    #pragma unroll
    for (int s = 0; s < NS; ++s)
        #pragma unroll
        for (int t = 0; t < 4; ++t)
            wf[s][t] = Wf[(s * 4 + t) * 64 + l];

    f32x4 acc[4];
    #pragma unroll
    for (int t = 0; t < 4; ++t) acc[t] = (f32x4){0.f, 0.f, 0.f, 0.f};

    #pragma unroll
    for (int s = 0; s < NS; ++s) {
        short8 af = {0, 0, 0, 0, 0, 0, 0, 0};
        if (A_BF16) {
            if (rok)
                af = *(const short8*)((const short*)inv + (long)arow * K + s * 32 + kgrp * 8);
        } else {
            if (rok) {
                const float* ap = (const float*)inv + (long)arow * K + s * 32 + kgrp * 8;
                float4 a0 = *(const float4*)ap;
                float4 a1 = *(const float4*)(ap + 4);
                af[0] = (short)f2bf(a0.x); af[1] = (short)f2bf(a0.y);
                af[2] = (short)f2bf(a0.z); af[3] = (short)f2bf(a0.w);
                af[4] = (short)f2bf(a1.x); af[5] = (short)f2bf(a1.y);
                af[6] = (short)f2bf(a1.z); af[7] = (short)f2bf(a1.w);
            }
        }
        #pragma unroll
        for (int t = 0; t < 4; ++t)
            acc[t] = __builtin_amdgcn_mfma_f32_16x16x32_bf16(af, wf[s][t], acc[t], 0, 0, 0);
    }

    // C/D layout: col = lane&15, row = (lane>>4)*4 + reg  [m89-verified]
    int orow0 = rows0 + kgrp * 4;
    #pragma unroll
    for (int t = 0; t < 4; ++t) {
        int col = t * 16 + (l & 15);
        float b = BIAS ? bias[col] : 0.f;
        #pragma unroll
        for (int r = 0; r < 4; ++r) {
            int row = orow0 + r;
            if (row < NN)
                out[(long)row * HID + col] = __float2bfloat16(acc[t][r] + b);
        }
    }
}

// ---------------- aggregate v2: edge-parallel, run-length register accumulation ----------------
// block owns dsts [d0, d0+DR); 4 waves split the edge range evenly. Per 64-edge
// batch: coalesced loads of src/dst/ws; readlane broadcasts give 16 independent
// row-gathers in flight; register acc flushed to LDS only on dst change.
__global__ __launch_bounds__(256) void agg2_k(const unsigned short* __restrict__ hw,
                                              const int* __restrict__ off,
                                              const int* __restrict__ csrc,
                                              const int* __restrict__ cdst,
                                              const float* __restrict__ ws,
                                              const float* __restrict__ dinv,
                                              const float* __restrict__ scsh,
                                              unsigned short* __restrict__ out) {
    __shared__ float accs[DR * HID];   // 16 KB
    int t = threadIdx.x;
    int lane = t & 63;
    int wid = t >> 6;
    int d0 = blockIdx.x * DR;
    int dhi = d0 + DR; if (dhi > NN) dhi = NN;

    #pragma unroll
    for (int j = 0; j < DR * HID / 256; ++j) accs[t + j * 256] = 0.f;
    __syncthreads();

    int e0b = off[d0];
    int e1b = off[dhi];
    int m = e1b - e0b;
    int mw = (m + 3) >> 2;
    int wstart = e0b + wid * mw;
    int wend = wstart + mw; if (wend > e1b) wend = e1b;

    float acc = 0.f;
    int cur_d = -1;
    for (int eb = wstart; eb < wend; eb += 64) {
        int ee = eb + lane;
        bool ok = ee < wend;
        int svec = ok ? csrc[ee] : 0;
        int dvec = ok ? cdst[ee] : -1;
        float wvec = ok ? ws[ee] : 0.f;
        int wbits = __float_as_uint(wvec);
        #pragma unroll
        for (int jb = 0; jb < 64; jb += 16) {
            unsigned short hv[16];
            #pragma unroll
            for (int j = 0; j < 16; ++j) {
                int s = __builtin_amdgcn_readlane(svec, jb + j);
                hv[j] = hw[(long)s * HID + lane];     // 16 gathers in flight
            }
            #pragma unroll
            for (int j = 0; j < 16; ++j) {
                int d = __builtin_amdgcn_readlane(dvec, jb + j);
                float w = __uint_as_float((unsigned)__builtin_amdgcn_readlane(wbits, jb + j));
                if (d != cur_d) {                      // wave-uniform branch
                    if (cur_d >= 0) atomicAdd(&accs[(cur_d - d0) * HID + lane], acc);
                    acc = 0.f;
                    cur_d = d;
                }
                acc += w * bf2f(hv[j]);
            }
        }
    }
    if (cur_d >= 0) atomicAdd(&accs[(cur_d - d0) * HID + lane], acc);
    __syncthreads();

    // epilogue: self loop + *dinv[d] + BN + ReLU, coalesced store
    float sc = scsh[lane];
    float sh = scsh[64 + lane];
    for (int dd = wid; dd < DR; dd += 4) {
        int d = d0 + dd;
        if (d >= NN) break;
        float dv = dinv[d];
        float v = (accs[dd * HID + lane] + bf2f(hw[(long)d * HID + lane]) * dv) * dv;
        out[(long)d * HID + lane] = f2bf(fmaxf(v * sc + sh, 0.f));
    }
}

// ---------------- pooling stage 1: parallel segmented sum over sorted batch ----------------
__global__ __launch_bounds__(256) void pool1_k(const __hip_bfloat16* __restrict__ h,
                                               const int* __restrict__ batch,
                                               float* __restrict__ sums) {
    int lane = threadIdx.x & 63;
    int wid = threadIdx.x >> 6;
    int chunk = blockIdx.x * 4 + wid;
    int i0 = chunk * 64;
    if (i0 >= NN) return;
    int i1 = i0 + 64;
    if (i1 > NN) i1 = NN;
    int g = batch[i0];
    float acc = 0.f;
    for (int i = i0; i < i1; ++i) {
        int bi = batch[i];
        if (bi != g) {
            atomicAdd(&sums[g * HID + lane], acc);
            acc = 0.f;
            g = bi;
        }
        acc += __bfloat162float(h[(long)i * HID + lane]);
    }
    atomicAdd(&sums[g * HID + lane], acc);
}

// ---------------- pooling stage 2 + 3-layer MLP, one block per graph ----------------
__device__ __forceinline__ int lower_bound_i(const int* __restrict__ a, int n, int key) {
    int lo = 0, hi = n;
    while (lo < hi) {
        int m = (lo + hi) >> 1;
        if (a[m] < key) lo = m + 1; else hi = m;
    }
    return lo;
}

__global__ __launch_bounds__(64) void mlp_k(const float* __restrict__ sums,
                                            const int* __restrict__ batch,
                                            const float* __restrict__ W1, const float* __restrict__ b1,
                                            const float* __restrict__ W2, const float* __restrict__ b2,
                                            const float* __restrict__ W3, const float* __restrict__ b3,
                                            float* __restrict__ out) {
    int g = blockIdx.x;
    int lane = threadIdx.x;
    int start = lower_bound_i(batch, NN, g);
    int end = lower_bound_i(batch, NN, g + 1);
    float cnt = (float)(end - start);
    float gv = sums[g * HID + lane] / fmaxf(cnt, 1.0f);

    __shared__ float gs[HID];
    __shared__ float h1s[HID];
    gs[lane] = gv;
    __syncthreads();

    float a1 = b1[lane];
    #pragma unroll 8
    for (int k = 0; k < HID; ++k) a1 += gs[k] * W1[k * HID + lane];
    a1 = fmaxf(a1, 0.f);
    h1s[lane] = a1;
    __syncthreads();

    float a2 = 0.f;
    if (lane < 32) {
        a2 = b2[lane];
        #pragma unroll 8
        for (int k = 0; k < HID; ++k) a2 += h1s[k] * W2[k * 32 + lane];
        a2 = fmaxf(a2, 0.f);
    }
    float p = (lane < 32) ? a2 * W3[lane] : 0.f;
    #pragma unroll
    for (int d = 32; d >= 1; d >>= 1) p += __shfl_down(p, d, 64);
    if (lane == 0) out[g] = p + b3[0];
}

// ---------------- host launch ----------------
extern "C" void kernel_launch(void* const* d_in, const int* in_sizes, int n_in,
                              void* d_out, int out_size, void* d_ws, size_t ws_size,
                              hipStream_t stream) {
    (void)in_sizes; (void)n_in; (void)out_size; (void)ws_size;

    const float* x      = (const float*)d_in[0];
    const int*   eidx   = (const int*)d_in[1];      // [2,E]: src then dst
    const int*   batch  = (const int*)d_in[2];
    const float* W_in   = (const float*)d_in[3];
    const float* b_in   = (const float*)d_in[4];
    const float* conv_W = (const float*)d_in[5];    // [3,64,64]
    const float* conv_b = (const float*)d_in[6];    // [3,64]
    const float* gamma  = (const float*)d_in[7];
    const float* beta   = (const float*)d_in[8];
    const float* mean   = (const float*)d_in[9];
    const float* var    = (const float*)d_in[10];
    const float* W1     = (const float*)d_in[11];
    const float* b1     = (const float*)d_in[12];
    const float* W2     = (const float*)d_in[13];
    const float* b2     = (const float*)d_in[14];
    const float* W3     = (const float*)d_in[15];
    const float* b3     = (const float*)d_in[16];
    float* outp = (float*)d_out;

    int*   wsi = (int*)d_ws;
    float* wsf = (float*)d_ws;

    int*   off    = wsi + I_OFF;
    int*   deg    = wsi + I_DEG;
    int*   hist   = wsi + I_HIST;
    int*   hs     = wsi + I_HS;
    int*   bsums  = wsi + I_BS;
    int*   boffs  = wsi + I_BO;
    int2*  pair   = (int2*)(wsi + I_PAIR);
    int*   csrc   = wsi + I_SRCS;
    int*   cdst   = wsi + I_DST;
    float* dinv   = wsf + I_DINV;
    float* Wc     = wsf + I_WC;
    short* WfA    = (short*)(wsi + I_WFA);
    short* Wf1    = (short*)(wsi + I_WF1);
    short* Wf2    = (short*)(wsi + I_WF2);
    __hip_bfloat16* bufA = (__hip_bfloat16*)(wsf + I_BUFA);
    __hip_bfloat16* bufB = (__hip_bfloat16*)(wsf + I_BUFB);
    float* sums   = wsf + I_SUMS;
    float* scsh   = wsf + I_SCSH;
    float* ws     = wsf + I_WS;

    const int* esrc = eidx;
    const int* edst = eidx + EE;

    hipMemsetAsync(sums, 0, NGRAPH * HID * sizeof(float), stream);

    // ---- graph prep: two-level counting sort -> deg, off, csrc, cdst
    hist_k<<<NCHUNK, 256, 0, stream>>>(edst, hist);
    int nb1 = (MHIST + 1023) / 1024;                 // 75
    scan1_k<<<nb1, 256, 0, stream>>>(hist, hs, bsums, MHIST);
    scan2_k<<<1, 128, 0, stream>>>(bsums, boffs, nb1);
    scan3g_k<<<(MHIST + 255) / 256, 256, 0, stream>>>(hs, boffs, MHIST);
    wc_k<<<(NODE_DIM * HID + HID + 255) / 256, 256, 0, stream>>>(W_in, b_in, conv_W, Wc);
    wfrag_k<<<8, 256, 0, stream>>>(Wc, conv_W, WfA, Wf1, Wf2);
    bnprep_k<<<3, 64, 0, stream>>>(conv_b, gamma, beta, mean, var, scsh);
    sortB_k<<<NCHUNK, 256, 0, stream>>>(esrc, edst, hs, pair);
    fineC_k<<<NB, 256, 0, stream>>>(pair, hs, deg, off, csrc, cdst);
    dinv_k<<<(NN + 255) / 256, 256, 0, stream>>>(deg, dinv, NN);
    wsrc_k<<<(EE + 255) / 256, 256, 0, stream>>>(csrc, dinv, ws);

    int ngemm = (NN + 63) / 64;                 // 1563
    int nagg  = (NN + DR - 1) / DR;             // 1563
    // layer 0: fused input projection + conv transform (A = x, fp32)
    gemm_k<NODE_DIM, true, false><<<ngemm, 256, 0, stream>>>(x, (const short8*)WfA,
                                                             Wc + NODE_DIM * HID, bufA);
    agg2_k<<<nagg, 256, 0, stream>>>((const unsigned short*)bufA, off, csrc, cdst, ws, dinv,
                                     scsh + 0 * 128, (unsigned short*)bufB);
    // layer 1 (A = bufB, bf16)
    gemm_k<HID, false, true><<<ngemm, 256, 0, stream>>>(bufB, (const short8*)Wf1, nullptr, bufA);
    agg2_k<<<nagg, 256, 0, stream>>>((const unsigned short*)bufA, off, csrc, cdst, ws, dinv,
                                     scsh + 1 * 128, (unsigned short*)bufB);
    // layer 2
    gemm_k<HID, false, true><<<ngemm, 256, 0, stream>>>(bufB, (const short8*)Wf2, nullptr, bufA);
    agg2_k<<<nagg, 256, 0, stream>>>((const unsigned short*)bufA, off, csrc, cdst, ws, dinv,
                                     scsh + 2 * 128, (unsigned short*)bufB);

    // mean pool (parallel) + MLP
    pool1_k<<<(NN / 64 + 3) / 4, 256, 0, stream>>>(bufB, batch, sums);
    mlp_k<<<NGRAPH, 64, 0, stream>>>(sums, batch, W1, b1, W2, b2, W3, b3, outp);
}

// Round 10
// 411.795 us; speedup vs baseline: 1.1066x; 1.0175x over previous
//
#include <hip/hip_runtime.h>
#include <hip/hip_bf16.h>

// Problem constants (fixed by the reference)
#define NN 100000
#define EE 1600000
#define ETOT 1700000      // EE + NN self-edges
#define NODE_DIM 128
#define HID 64
#define NGRAPH 256
#define BN_EPS 1e-5f

// counting-sort geometry
#define NB 196            // coarse buckets: dst>>9  (99999>>9 == 195)
#define BW 512            // bucket width (power of 2)
#define CH 16384          // edges per chunk (long runs -> full-line scatter)
#define NCHUNK 98         // ceil(EE/CH)
#define MHIST (NB * NCHUNK)   // 19208
#define MAXB 12288        // LDS capacity per bucket (avg 8192+512 selfs)

// aggregate geometry
#define GD 16             // dsts per wave

typedef __attribute__((ext_vector_type(8))) short short8;   // 8 bf16 (4 VGPRs)
typedef __attribute__((ext_vector_type(4))) float f32x4;    // MFMA acc

// RNE float->bf16 (bit-exact)
static __device__ __forceinline__ unsigned short f2bf(float f) {
    unsigned u = __float_as_uint(f);
    unsigned r = (u + 0x7fffu + ((u >> 16) & 1u)) >> 16;
    return (unsigned short)r;
}
static __device__ __forceinline__ float bf2f(unsigned short u) {
    return __uint_as_float(((unsigned)u) << 16);
}

// ---------------- workspace layout (units of 4 bytes) ----------------
#define I_OFF   0                 // int[NN+1]
#define I_DEG   100032            // int[NN]
#define I_HIST  200064            // int[MHIST]
#define I_HS    219328            // int[MHIST]
#define I_BS    238592            // int[128]
#define I_BO    238720            // int[128]
#define I_PAIR  238848            // int2[EE] (3,200,000 words)
#define I_SRCS  3438848           // int[ETOT+pad]
#define I_DST   5138944           // int[ETOT+pad]
#define I_WS    6839040           // float[ETOT+pad]
#define I_DINV  8539136           // float[NN]
#define I_WC    8639168           // float[128*64 + 64]
#define I_WFA   8647424           // bf16[128*64]
#define I_WF1   8651520           // bf16[64*64]
#define I_WF2   8653568           // bf16[64*64]
#define I_BUFA  8655616           // bf16[NN*64]
#define I_BUFB  11855616          // bf16[NN*64]
#define I_SUMS  15055616          // float[NGRAPH*HID]
#define I_SCSH  15072000          // float[3*128]
// end = 15,072,384 words = 60.3 MB

// ---------------- pass A: per-chunk coarse histogram ----------------
__global__ __launch_bounds__(256) void hist_k(const int* __restrict__ dst,
                                              int* __restrict__ hist) {
    __shared__ int h[NB];
    for (int i = threadIdx.x; i < NB; i += 256) h[i] = 0;
    __syncthreads();
    int base = blockIdx.x * CH + threadIdx.x;
    for (int j = 0; j < CH / 256; ++j) {
        int e = base + j * 256;
        if (e < EE) {
            int d = __builtin_nontemporal_load(dst + e);
            atomicAdd(&h[d >> 9], 1);
        }
    }
    __syncthreads();
    for (int i = threadIdx.x; i < NB; i += 256)
        hist[i * NCHUNK + blockIdx.x] = h[i];   // bucket-major for the scan
}

// ---------------- generic exclusive scan (3 stages) ----------------
__global__ void scan1_k(const int* __restrict__ in, int* __restrict__ part,
                        int* __restrict__ bsums, int n) {
    __shared__ int wsum[4];
    __shared__ int woff[4];
    int t = threadIdx.x;
    int base = blockIdx.x * 1024 + t * 4;
    int v0 = 0, v1 = 0, v2 = 0, v3 = 0;
    if (base + 3 < n) {
        v0 = in[base]; v1 = in[base + 1]; v2 = in[base + 2]; v3 = in[base + 3];
    } else {
        if (base     < n) v0 = in[base];
        if (base + 1 < n) v1 = in[base + 1];
        if (base + 2 < n) v2 = in[base + 2];
    }
    int s = v0 + v1 + v2 + v3;
    int lane = t & 63, wid = t >> 6;
    int x = s;
    #pragma unroll
    for (int d = 1; d < 64; d <<= 1) {
        int y = __shfl_up(x, d, 64);
        if (lane >= d) x += y;
    }
    if (lane == 63) wsum[wid] = x;
    __syncthreads();
    if (t == 0) {
        int r = 0;
        for (int w = 0; w < 4; ++w) { woff[w] = r; r += wsum[w]; }
        bsums[blockIdx.x] = r;
    }
    __syncthreads();
    int ex = woff[wid] + (x - s);
    if (base     < n) part[base]     = ex;
    if (base + 1 < n) part[base + 1] = ex + v0;
    if (base + 2 < n) part[base + 2] = ex + v0 + v1;
    if (base + 3 < n) part[base + 3] = ex + v0 + v1 + v2;
}

__global__ void scan2_k(const int* __restrict__ bsums, int* __restrict__ boffs, int nb) {
    __shared__ int wsum[2];
    __shared__ int woff2[2];
    int t = threadIdx.x;
    int v = (t < nb) ? bsums[t] : 0;
    int lane = t & 63, wid = t >> 6;
    int x = v;
    #pragma unroll
    for (int d = 1; d < 64; d <<= 1) {
        int y = __shfl_up(x, d, 64);
        if (lane >= d) x += y;
    }
    if (lane == 63) wsum[wid] = x;
    __syncthreads();
    if (t == 0) { woff2[0] = 0; woff2[1] = wsum[0]; }
    __syncthreads();
    int ex = woff2[wid] + (x - v);
    if (t < nb) boffs[t] = ex;
}

__global__ void scan3g_k(int* __restrict__ arr, const int* __restrict__ boffs, int n) {
    int i = blockIdx.x * 256 + threadIdx.x;
    if (i < n) arr[i] += boffs[i >> 10];
}

// ---------------- pass B: coarse placement (dst,src) pairs by bucket ----------------
__global__ __launch_bounds__(256) void sortB_k(const int* __restrict__ srcA,
                                               const int* __restrict__ dstA,
                                               const int* __restrict__ hs,
                                               int2* __restrict__ pair) {
    __shared__ int lcur[NB];
    for (int i = threadIdx.x; i < NB; i += 256)
        lcur[i] = hs[i * NCHUNK + blockIdx.x];
    __syncthreads();
    int base = blockIdx.x * CH + threadIdx.x;
    for (int j = 0; j < CH / 256; ++j) {
        int e = base + j * 256;
        if (e < EE) {
            int d = __builtin_nontemporal_load(dstA + e);
            int s = __builtin_nontemporal_load(srcA + e);
            int pos = atomicAdd(&lcur[d >> 9], 1);
            pair[pos] = make_int2(d, s);
        }
    }
}

// ---------------- pass C: per-bucket exact sort in LDS + SELF-EDGE insertion ----------------
// emits deg (real), off (incl selfs), csrc/cdst (self-edge first per run).
__global__ __launch_bounds__(256) void fineC_k(const int2* __restrict__ pair,
                                               const int* __restrict__ hs,
                                               int* __restrict__ deg,
                                               int* __restrict__ off,
                                               int* __restrict__ csrc,
                                               int* __restrict__ cdst) {
    __shared__ int cnt[BW];
    __shared__ int loff[BW];
    __shared__ int wsum[4];
    __shared__ int woff[4];
    __shared__ int ssrc[MAXB];
    __shared__ int sdst[MAXB];
    int b = blockIdx.x;
    int t = threadIdx.x;
    int base_r = hs[b * NCHUNK];
    int end_r  = (b == NB - 1) ? EE : hs[(b + 1) * NCHUNK];
    int m = end_r - base_r;
    int node0 = b << 9;
    int base_out = base_r + b * BW;   // + selfs of all previous (full) buckets

    for (int i = t; i < BW; i += 256) cnt[i] = 0;
    __syncthreads();
    for (int i = t; i < m; i += 256) {
        int2 p = pair[base_r + i];
        atomicAdd(&cnt[p.x & (BW - 1)], 1);
    }
    __syncthreads();

    // real degree out (before self insertion)
    for (int i = t; i < BW; i += 256) {
        int node = node0 + i;
        if (node < NN) deg[node] = cnt[i];
    }

    // block exclusive scan of (cnt + self) over 512 entries
    int va = (node0 + 2 * t)     < NN ? 1 : 0;
    int vb = (node0 + 2 * t + 1) < NN ? 1 : 0;
    int c0 = cnt[2 * t] + va, c1 = cnt[2 * t + 1] + vb;
    int s = c0 + c1;
    int lane = t & 63, wid = t >> 6;
    int x = s;
    #pragma unroll
    for (int d = 1; d < 64; d <<= 1) {
        int y = __shfl_up(x, d, 64);
        if (lane >= d) x += y;
    }
    if (lane == 63) wsum[wid] = x;
    __syncthreads();
    if (t == 0) {
        int r = 0;
        for (int w = 0; w < 4; ++w) { woff[w] = r; r += wsum[w]; }
    }
    __syncthreads();
    int ex = woff[wid] + (x - s);
    loff[2 * t] = ex;
    loff[2 * t + 1] = ex + c0;
    __syncthreads();

    // node offsets (include selfs)
    for (int i = t; i < BW; i += 256) {
        int node = node0 + i;
        if (node < NN) off[node] = base_out + loff[i];
        else if (node == NN) off[NN] = ETOT;
    }

    // place self-edge first in each run; init cursors after it
    for (int i = t; i < BW; i += 256) {
        int node = node0 + i;
        int p = loff[i];
        if (node < NN) {
            if (p < MAXB) { ssrc[p] = node; sdst[p] = node; }
            else { csrc[base_out + p] = node; cdst[base_out + p] = node; }
            cnt[i] = p + 1;
        } else {
            cnt[i] = p;
        }
    }
    __syncthreads();

    for (int i = t; i < m; i += 256) {
        int2 p = pair[base_r + i];
        int pos = atomicAdd(&cnt[p.x & (BW - 1)], 1);
        if (pos < MAXB) { ssrc[pos] = p.y; sdst[pos] = p.x; }
        else { csrc[base_out + pos] = p.y; cdst[base_out + pos] = p.x; }
    }
    __syncthreads();

    int nvalid = (b == NB - 1) ? (NN - node0) : BW;
    int mo = m + nvalid;
    int mm = mo < MAXB ? mo : MAXB;
    for (int i = t; i < mm; i += 256) {   // coalesced copy-out
        csrc[base_out + i] = ssrc[i];
        cdst[base_out + i] = sdst[i];
    }
}

__global__ void dinv_k(const int* __restrict__ cnt, float* __restrict__ dinv, int n) {
    int i = blockIdx.x * 256 + threadIdx.x;
    if (i < n) dinv[i] = rsqrtf((float)(cnt[i] + 1));   // +1 self loop
}

// per-edge source weight: ws[e] = dinv[csrc[e]] (self-edges handled automatically)
__global__ void wsrc_k(const int* __restrict__ csrc, const float* __restrict__ dinv,
                       float* __restrict__ ws) {
    int e = blockIdx.x * 256 + threadIdx.x;
    if (e < ETOT) ws[e] = dinv[csrc[e]];
}

// ---------------- BN scale/shift table ----------------
__global__ void bnprep_k(const float* __restrict__ convb, const float* __restrict__ gamma,
                         const float* __restrict__ beta, const float* __restrict__ mean,
                         const float* __restrict__ var, float* __restrict__ scsh) {
    int t = blockIdx.x * 64 + threadIdx.x;   // grid 3 x 64
    int l = t >> 6, c = t & 63;
    float sc = gamma[l * 64 + c] * rsqrtf(var[l * 64 + c] + BN_EPS);
    float sh = (convb[l * 64 + c] - mean[l * 64 + c]) * sc + beta[l * 64 + c];
    scsh[l * 128 + c] = sc;
    scsh[l * 128 + 64 + c] = sh;
}

// ---------------- fused input-proj weight: Wc = W_in @ conv_W0, bc = b_in @ conv_W0 ----------------
__global__ void wc_k(const float* __restrict__ Win, const float* __restrict__ bin,
                     const float* __restrict__ cw0, float* __restrict__ Wc) {
    int idx = blockIdx.x * 256 + threadIdx.x;
    if (idx < NODE_DIM * HID) {
        int k = idx >> 6, c = idx & 63;
        float a = 0.f;
        #pragma unroll 8
        for (int j = 0; j < HID; ++j) a += Win[k * HID + j] * cw0[j * HID + c];
        Wc[idx] = a;
    } else if (idx < NODE_DIM * HID + HID) {
        int c = idx - NODE_DIM * HID;
        float a = 0.f;
        #pragma unroll 8
        for (int j = 0; j < HID; ++j) a += bin[j] * cw0[j * HID + c];
        Wc[idx] = a;
    }
}

// ---------------- pack W into MFMA B-fragment order (bf16) ----------------
__global__ __launch_bounds__(256) void wfrag_k(const float* __restrict__ Wc,
                                               const float* __restrict__ convW,
                                               short* __restrict__ WfA,
                                               short* __restrict__ Wf1,
                                               short* __restrict__ Wf2) {
    int id = blockIdx.x * 256 + threadIdx.x;   // 0..2047
    const float* W; short* out; int u;
    if (id < 1024)      { W = Wc;           out = WfA; u = id; }
    else if (id < 1536) { W = convW + 4096; out = Wf1; u = id - 1024; }
    else                { W = convW + 8192; out = Wf2; u = id - 1536; }
    int l = u & 63, t = (u >> 6) & 3, s = u >> 8;
    int k0 = s * 32 + ((l >> 4) & 3) * 8;
    int col = t * 16 + (l & 15);
    short8 v;
    #pragma unroll
    for (int j = 0; j < 8; ++j) v[j] = (short)f2bf(W[(k0 + j) * 64 + col]);
    *(short8*)(out + u * 8) = v;
}

// ---------------- MFMA transform: out[n,64] = bf16(in[n,K] @ W[K,64] (+bias)) ----------------
template <int K, bool BIAS, bool A_BF16>
__global__ __launch_bounds__(256, 4) void gemm_k(const void* __restrict__ inv,
                                                 const short8* __restrict__ Wf,
                                                 const float* __restrict__ bias,
                                                 __hip_bfloat16* __restrict__ out) {
    constexpr int NS = K / 32;
    int l = threadIdx.x & 63;
    int w = threadIdx.x >> 6;
    int rows0 = blockIdx.x * 64 + w * 16;
    int arow = rows0 + (l & 15);
    bool rok = arow < NN;
    int kgrp = (l >> 4) & 3;

    short8 wf[NS][4];
    #pragma unroll
    for (int s = 0; s < NS; ++s)
        #pragma unroll
        for (int t = 0; t < 4; ++t)
            wf[s][t] = Wf[(s * 4 + t) * 64 + l];

    f32x4 acc[4];
    #pragma unroll
    for (int t = 0; t < 4; ++t) acc[t] = (f32x4){0.f, 0.f, 0.f, 0.f};

    #pragma unroll
    for (int s = 0; s < NS; ++s) {
        short8 af = {0, 0, 0, 0, 0, 0, 0, 0};
        if (A_BF16) {
            if (rok)
                af = *(const short8*)((const short*)inv + (long)arow * K + s * 32 + kgrp * 8);
        } else {
            if (rok) {
                const float* ap = (const float*)inv + (long)arow * K + s * 32 + kgrp * 8;
                float4 a0 = *(const float4*)ap;
                float4 a1 = *(const float4*)(ap + 4);
                af[0] = (short)f2bf(a0.x); af[1] = (short)f2bf(a0.y);
                af[2] = (short)f2bf(a0.z); af[3] = (short)f2bf(a0.w);
                af[4] = (short)f2bf(a1.x); af[5] = (short)f2bf(a1.y);
                af[6] = (short)f2bf(a1.z); af[7] = (short)f2bf(a1.w);
            }
        }
        #pragma unroll
        for (int t = 0; t < 4; ++t)
            acc[t] = __builtin_amdgcn_mfma_f32_16x16x32_bf16(af, wf[s][t], acc[t], 0, 0, 0);
    }

    // C/D layout: col = lane&15, row = (lane>>4)*4 + reg  [m89-verified]
    int orow0 = rows0 + kgrp * 4;
    #pragma unroll
    for (int t = 0; t < 4; ++t) {
        int col = t * 16 + (l & 15);
        float b = BIAS ? bias[col] : 0.f;
        #pragma unroll
        for (int r = 0; r < 4; ++r) {
            int row = orow0 + r;
            if (row < NN)
                out[(long)row * HID + col] = __float2bfloat16(acc[t][r] + b);
        }
    }
}

// ---------------- aggregate v3: wave-private run-length walk, no LDS ----------------
// wave owns dsts [dw0, dw0+GD); self-edges guarantee every dst appears.
// Per 64-edge batch: coalesced src/dst/ws loads; boundary bitmask via ballot
// (scalar tests in the walk); 32 gathers in flight with scalar-base addressing.
__global__ __launch_bounds__(256) void agg3_k(const unsigned short* __restrict__ hw,
                                              const int* __restrict__ off,
                                              const int* __restrict__ csrc,
                                              const int* __restrict__ cdst,
                                              const float* __restrict__ ws,
                                              const float* __restrict__ dinv,
                                              const float* __restrict__ scsh,
                                              unsigned short* __restrict__ out) {
    int lane = threadIdx.x & 63;
    int wid = threadIdx.x >> 6;
    int dw0 = blockIdx.x * 64 + wid * GD;
    if (dw0 >= NN) return;
    int dw1 = dw0 + GD; if (dw1 > NN) dw1 = NN;
    int e0 = off[dw0], e1 = off[dw1];
    float sc = scsh[lane];
    float sh = scsh[64 + lane];
    const char* hwb = (const char*)hw;
    int laneOfs = lane * 2;

    int cur_d = -1;
    float acc = 0.f;
    for (int eb = e0; eb < e1; eb += 64) {
        int ee = eb + lane;
        bool ok = ee < e1;
        int ec = ok ? ee : (e1 - 1);
        int svec = csrc[ec];
        int dvec = ok ? cdst[ec] : NN;          // sentinel past end
        float wv = ok ? ws[ec] : 0.f;
        unsigned sofs = ((unsigned)svec) << 7;  // src * 128 bytes
        unsigned wbits = __float_as_uint(wv);

        int dprev = __shfl_up(dvec, 1, 64);
        unsigned long long bmask = __ballot(dvec != dprev);
        int d00 = __builtin_amdgcn_readfirstlane(dvec);
        if (d00 != cur_d) bmask |= 1ull; else bmask &= ~1ull;

        #pragma unroll
        for (int h = 0; h < 2; ++h) {
            unsigned short hv[32];
            #pragma unroll
            for (int j = 0; j < 32; ++j) {
                unsigned so = (unsigned)__builtin_amdgcn_readlane((int)sofs, h * 32 + j);
                hv[j] = *(const unsigned short*)(hwb + so + laneOfs);  // saddr + lane
            }
            #pragma unroll
            for (int j = 0; j < 32; ++j) {
                int jj = h * 32 + j;
                if ((bmask >> jj) & 1ull) {     // scalar bit test, wave-uniform
                    if (cur_d >= 0) {
                        float v = acc * dinv[cur_d];
                        out[(long)cur_d * HID + lane] = f2bf(fmaxf(v * sc + sh, 0.f));
                    }
                    acc = 0.f;
                    cur_d = __builtin_amdgcn_readlane(dvec, jj);
                }
                float w = __uint_as_float((unsigned)__builtin_amdgcn_readlane((int)wbits, jj));
                acc += w * bf2f(hv[j]);
            }
        }
    }
    if (cur_d >= 0 && cur_d < NN) {
        float v = acc * dinv[cur_d];
        out[(long)cur_d * HID + lane] = f2bf(fmaxf(v * sc + sh, 0.f));
    }
}

// ---------------- pooling stage 1: parallel segmented sum over sorted batch ----------------
__global__ __launch_bounds__(256) void pool1_k(const __hip_bfloat16* __restrict__ h,
                                               const int* __restrict__ batch,
                                               float* __restrict__ sums) {
    int lane = threadIdx.x & 63;
    int wid = threadIdx.x >> 6;
    int chunk = blockIdx.x * 4 + wid;
    int i0 = chunk * 64;
    if (i0 >= NN) return;
    int i1 = i0 + 64;
    if (i1 > NN) i1 = NN;
    int g = batch[i0];
    float acc = 0.f;
    for (int i = i0; i < i1; ++i) {
        int bi = batch[i];
        if (bi != g) {
            atomicAdd(&sums[g * HID + lane], acc);
            acc = 0.f;
            g = bi;
        }
        acc += __bfloat162float(h[(long)i * HID + lane]);
    }
    atomicAdd(&sums[g * HID + lane], acc);
}

// ---------------- pooling stage 2 + 3-layer MLP, one block per graph ----------------
__device__ __forceinline__ int lower_bound_i(const int* __restrict__ a, int n, int key) {
    int lo = 0, hi = n;
    while (lo < hi) {
        int m = (lo + hi) >> 1;
        if (a[m] < key) lo = m + 1; else hi = m;
    }
    return lo;
}

__global__ __launch_bounds__(64) void mlp_k(const float* __restrict__ sums,
                                            const int* __restrict__ batch,
                                            const float* __restrict__ W1, const float* __restrict__ b1,
                                            const float* __restrict__ W2, const float* __restrict__ b2,
                                            const float* __restrict__ W3, const float* __restrict__ b3,
                                            float* __restrict__ out) {
    int g = blockIdx.x;
    int lane = threadIdx.x;
    int start = lower_bound_i(batch, NN, g);
    int end = lower_bound_i(batch, NN, g + 1);
    float cnt = (float)(end - start);
    float gv = sums[g * HID + lane] / fmaxf(cnt, 1.0f);

    __shared__ float gs[HID];
    __shared__ float h1s[HID];
    gs[lane] = gv;
    __syncthreads();

    float a1 = b1[lane];
    #pragma unroll 8
    for (int k = 0; k < HID; ++k) a1 += gs[k] * W1[k * HID + lane];
    a1 = fmaxf(a1, 0.f);
    h1s[lane] = a1;
    __syncthreads();

    float a2 = 0.f;
    if (lane < 32) {
        a2 = b2[lane];
        #pragma unroll 8
        for (int k = 0; k < HID; ++k) a2 += h1s[k] * W2[k * 32 + lane];
        a2 = fmaxf(a2, 0.f);
    }
    float p = (lane < 32) ? a2 * W3[lane] : 0.f;
    #pragma unroll
    for (int d = 32; d >= 1; d >>= 1) p += __shfl_down(p, d, 64);
    if (lane == 0) out[g] = p + b3[0];
}

// ---------------- host launch ----------------
extern "C" void kernel_launch(void* const* d_in, const int* in_sizes, int n_in,
                              void* d_out, int out_size, void* d_ws, size_t ws_size,
                              hipStream_t stream) {
    (void)in_sizes; (void)n_in; (void)out_size; (void)ws_size;

    const float* x      = (const float*)d_in[0];
    const int*   eidx   = (const int*)d_in[1];      // [2,E]: src then dst
    const int*   batch  = (const int*)d_in[2];
    const float* W_in   = (const float*)d_in[3];
    const float* b_in   = (const float*)d_in[4];
    const float* conv_W = (const float*)d_in[5];    // [3,64,64]
    const float* conv_b = (const float*)d_in[6];    // [3,64]
    const float* gamma  = (const float*)d_in[7];
    const float* beta   = (const float*)d_in[8];
    const float* mean   = (const float*)d_in[9];
    const float* var    = (const float*)d_in[10];
    const float* W1     = (const float*)d_in[11];
    const float* b1     = (const float*)d_in[12];
    const float* W2     = (const float*)d_in[13];
    const float* b2     = (const float*)d_in[14];
    const float* W3     = (const float*)d_in[15];
    const float* b3     = (const float*)d_in[16];
    float* outp = (float*)d_out;

    int*   wsi = (int*)d_ws;
    float* wsf = (float*)d_ws;

    int*   off    = wsi + I_OFF;
    int*   deg    = wsi + I_DEG;
    int*   hist   = wsi + I_HIST;
    int*   hs     = wsi + I_HS;
    int*   bsums  = wsi + I_BS;
    int*   boffs  = wsi + I_BO;
    int2*  pair   = (int2*)(wsi + I_PAIR);
    int*   csrc   = wsi + I_SRCS;
    int*   cdst   = wsi + I_DST;
    float* ws     = wsf + I_WS;
    float* dinv   = wsf + I_DINV;
    float* Wc     = wsf + I_WC;
    short* WfA    = (short*)(wsi + I_WFA);
    short* Wf1    = (short*)(wsi + I_WF1);
    short* Wf2    = (short*)(wsi + I_WF2);
    __hip_bfloat16* bufA = (__hip_bfloat16*)(wsf + I_BUFA);
    __hip_bfloat16* bufB = (__hip_bfloat16*)(wsf + I_BUFB);
    float* sums   = wsf + I_SUMS;
    float* scsh   = wsf + I_SCSH;

    const int* esrc = eidx;
    const int* edst = eidx + EE;

    hipMemsetAsync(sums, 0, NGRAPH * HID * sizeof(float), stream);

    // ---- graph prep: two-level counting sort (+ self-edges) -> deg, off, csrc, cdst
    hist_k<<<NCHUNK, 256, 0, stream>>>(edst, hist);
    int nb1 = (MHIST + 1023) / 1024;                 // 19
    scan1_k<<<nb1, 256, 0, stream>>>(hist, hs, bsums, MHIST);
    scan2_k<<<1, 128, 0, stream>>>(bsums, boffs, nb1);
    scan3g_k<<<(MHIST + 255) / 256, 256, 0, stream>>>(hs, boffs, MHIST);
    wc_k<<<(NODE_DIM * HID + HID + 255) / 256, 256, 0, stream>>>(W_in, b_in, conv_W, Wc);
    wfrag_k<<<8, 256, 0, stream>>>(Wc, conv_W, WfA, Wf1, Wf2);
    bnprep_k<<<3, 64, 0, stream>>>(conv_b, gamma, beta, mean, var, scsh);
    sortB_k<<<NCHUNK, 256, 0, stream>>>(esrc, edst, hs, pair);
    fineC_k<<<NB, 256, 0, stream>>>(pair, hs, deg, off, csrc, cdst);
    dinv_k<<<(NN + 255) / 256, 256, 0, stream>>>(deg, dinv, NN);
    wsrc_k<<<(ETOT + 255) / 256, 256, 0, stream>>>(csrc, dinv, ws);

    int ngemm = (NN + 63) / 64;                 // 1563
    int nagg  = (NN + 63) / 64;                 // 1563 (64 dsts per block)
    // layer 0: fused input projection + conv transform (A = x, fp32)
    gemm_k<NODE_DIM, true, false><<<ngemm, 256, 0, stream>>>(x, (const short8*)WfA,
                                                             Wc + NODE_DIM * HID, bufA);
    agg3_k<<<nagg, 256, 0, stream>>>((const unsigned short*)bufA, off, csrc, cdst, ws, dinv,
                                     scsh + 0 * 128, (unsigned short*)bufB);
    // layer 1 (A = bufB, bf16)
    gemm_k<HID, false, true><<<ngemm, 256, 0, stream>>>(bufB, (const short8*)Wf1, nullptr, bufA);
    agg3_k<<<nagg, 256, 0, stream>>>((const unsigned short*)bufA, off, csrc, cdst, ws, dinv,
                                     scsh + 1 * 128, (unsigned short*)bufB);
    // layer 2
    gemm_k<HID, false, true><<<ngemm, 256, 0, stream>>>(bufB, (const short8*)Wf2, nullptr, bufA);
    agg3_k<<<nagg, 256, 0, stream>>>((const unsigned short*)bufA, off, csrc, cdst, ws, dinv,
                                     scsh + 2 * 128, (unsigned short*)bufB);

    // mean pool (parallel) + MLP
    pool1_k<<<(NN / 64 + 3) / 4, 256, 0, stream>>>(bufB, batch, sums);
    mlp_k<<<NGRAPH, 64, 0, stream>>>(sums, batch, W1, b1, W2, b2, W3, b3, outp);
}